// Round 1
// baseline (1670.692 us; speedup 1.0000x reference)
//
#include <hip/hip_runtime.h>
#include <math.h>

#define TOK_STRIDE 768  // 12 heads * 64 dim, floats per token

__device__ __forceinline__ int inst_index(int g, int b, int seg, int gh) {
    if (g == 0) return b * 16 + seg * 4 + gh;
    if (g == 1) return 32 + b * 8 + seg * 4 + gh;
    return 48 + b * 4 + gh;
}

// -------------------- Pass 1: flash attention per instance --------------------
// grid: (32 row-tiles, 56 instances), block 256
// Each block: 64 Q-rows of one instance, loops over 32 key-tiles of 64.
// Thread (tx=t&15, ty=t>>4) owns a 4x4 micro-tile: rows r0..r0+3, cols c0..c0+3.
__global__ __launch_bounds__(256, 2) void attn_kernel(
    const float* __restrict__ Q, const float* __restrict__ K,
    const float* __restrict__ V, float* __restrict__ O)
{
    const int rt   = blockIdx.x;
    const int inst = blockIdx.y;

    int g, b, seg, gh;
    if (inst < 32)      { g = 0; int x = inst;      b = x >> 4; seg = (x >> 2) & 3; gh = x & 3; }
    else if (inst < 48) { g = 1; int x = inst - 32; b = x >> 3; seg = (x >> 2) & 1; gh = x & 3; }
    else                { g = 2; int x = inst - 48; b = x >> 2; seg = 0;            gh = x & 3; }

    const int  r    = 1 << g;                // dilation 1,2,4
    const int  s    = 2048 << g;             // segment 2048,4096,8192
    const int  off  = (g == 0) ? 0 : g;      // offset 0,1,2
    const int  h    = g * 4 + gh;

    const long tok0  = (long)seg * s + off;
    const long tstep = (long)r * TOK_STRIDE;  // float stride between dilated tokens
    const long base  = ((long)b * 8192 + tok0) * TOK_STRIDE + (long)h * 64;

    const float* qb = Q + base;
    const float* kb = K + base;
    const float* vb = V + base;

    __shared__ float Qt[64][68];  // [d][row]
    __shared__ float Kt[64][68];  // [d][key]
    __shared__ float Vs[64][68];  // [key][d]
    __shared__ float Pt[64][68];  // [key][row]

    const int t  = threadIdx.x;
    const int tx = t & 15, ty = t >> 4;
    const int r0 = ty * 4, c0 = tx * 4;

    // stage Q tile (transposed: Qt[d][row])
    #pragma unroll
    for (int p = 0; p < 4; ++p) {
        int flat = p * 256 + t;
        int row  = flat >> 4;
        int dq   = (flat & 15) * 4;
        float4 qv = *(const float4*)(qb + ((long)(rt * 64 + row)) * tstep + dq);
        Qt[dq + 0][row] = qv.x; Qt[dq + 1][row] = qv.y;
        Qt[dq + 2][row] = qv.z; Qt[dq + 3][row] = qv.w;
    }

    float m[4], l[4], o[4][4];
    #pragma unroll
    for (int i = 0; i < 4; ++i) {
        m[i] = -INFINITY; l[i] = 0.f;
        #pragma unroll
        for (int j = 0; j < 4; ++j) o[i][j] = 0.f;
    }

    __syncthreads();

    for (int kt = 0; kt < 32; ++kt) {
        // stage K (transposed) and V tiles
        #pragma unroll
        for (int p = 0; p < 4; ++p) {
            int flat = p * 256 + t;
            int row  = flat >> 4;
            int dq   = (flat & 15) * 4;
            const long ofs = ((long)(kt * 64 + row)) * tstep + dq;
            float4 kv = *(const float4*)(kb + ofs);
            Kt[dq + 0][row] = kv.x; Kt[dq + 1][row] = kv.y;
            Kt[dq + 2][row] = kv.z; Kt[dq + 3][row] = kv.w;
            float4 vv = *(const float4*)(vb + ofs);
            *(float4*)&Vs[row][dq] = vv;
        }
        __syncthreads();

        // ---- scores: S[4x4] = Q_rows . K_cols ----
        float sc[4][4];
        #pragma unroll
        for (int i = 0; i < 4; ++i)
            #pragma unroll
            for (int j = 0; j < 4; ++j) sc[i][j] = 0.f;

        #pragma unroll 16
        for (int dd = 0; dd < 64; ++dd) {
            float4 q4 = *(const float4*)&Qt[dd][r0];
            float4 k4 = *(const float4*)&Kt[dd][c0];
            float qa[4] = {q4.x, q4.y, q4.z, q4.w};
            float ka[4] = {k4.x, k4.y, k4.z, k4.w};
            #pragma unroll
            for (int i = 0; i < 4; ++i)
                #pragma unroll
                for (int j = 0; j < 4; ++j)
                    sc[i][j] = fmaf(qa[i], ka[j], sc[i][j]);
        }
        #pragma unroll
        for (int i = 0; i < 4; ++i)
            #pragma unroll
            for (int j = 0; j < 4; ++j) sc[i][j] *= 0.125f;

        // ---- online softmax (16-lane row groups) ----
        float pv[4][4];
        #pragma unroll
        for (int ri = 0; ri < 4; ++ri) {
            float mx = fmaxf(fmaxf(sc[ri][0], sc[ri][1]), fmaxf(sc[ri][2], sc[ri][3]));
            mx = fmaxf(mx, __shfl_xor(mx, 1));
            mx = fmaxf(mx, __shfl_xor(mx, 2));
            mx = fmaxf(mx, __shfl_xor(mx, 4));
            mx = fmaxf(mx, __shfl_xor(mx, 8));
            float mnew = fmaxf(m[ri], mx);
            float f    = __expf(m[ri] - mnew);   // exp(-inf)=0 on first tile
            float psum = 0.f;
            #pragma unroll
            for (int ci = 0; ci < 4; ++ci) {
                pv[ri][ci] = __expf(sc[ri][ci] - mnew);
                psum += pv[ri][ci];
            }
            psum += __shfl_xor(psum, 1);
            psum += __shfl_xor(psum, 2);
            psum += __shfl_xor(psum, 4);
            psum += __shfl_xor(psum, 8);
            l[ri] = l[ri] * f + psum;
            m[ri] = mnew;
            #pragma unroll
            for (int ci = 0; ci < 4; ++ci) o[ri][ci] *= f;
        }

        // write P transposed: Pt[key][row]
        #pragma unroll
        for (int ci = 0; ci < 4; ++ci) {
            float4 pw = make_float4(pv[0][ci], pv[1][ci], pv[2][ci], pv[3][ci]);
            *(float4*)&Pt[c0 + ci][r0] = pw;
        }
        __syncthreads();

        // ---- O += P * V ----
        #pragma unroll 16
        for (int kk = 0; kk < 64; ++kk) {
            float4 p4 = *(const float4*)&Pt[kk][r0];
            float4 v4 = *(const float4*)&Vs[kk][c0];
            float pa[4] = {p4.x, p4.y, p4.z, p4.w};
            float va[4] = {v4.x, v4.y, v4.z, v4.w};
            #pragma unroll
            for (int i = 0; i < 4; ++i)
                #pragma unroll
                for (int j = 0; j < 4; ++j)
                    o[i][j] = fmaf(pa[i], va[j], o[i][j]);
        }
        __syncthreads();
    }

    // epilogue: divide by softmax denom, write to workspace
    #pragma unroll
    for (int ri = 0; ri < 4; ++ri) {
        float inv = 1.0f / l[ri];
        float4 ov = make_float4(o[ri][0] * inv, o[ri][1] * inv, o[ri][2] * inv, o[ri][3] * inv);
        long row = (long)rt * 64 + r0 + ri;
        *(float4*)(O + ((long)inst * 2048 + row) * 64 + c0) = ov;
    }
}

// -------------------- Pass 2: per-(group,b,head,d) sums (double) --------------------
// grid 24 blocks (g*8 + b*4 + gh), block 256 (thread: d = t&63, row-chunk = t>>6)
__global__ __launch_bounds__(256) void sum_kernel(
    const float* __restrict__ O, double* __restrict__ sums)
{
    const int blk = blockIdx.x;
    const int g   = blk >> 3;
    const int b   = (blk >> 2) & 1;
    const int gh  = blk & 3;
    const int nseg = 4 >> g;

    const int t  = threadIdx.x;
    const int d  = t & 63;
    const int rc = t >> 6;

    double acc = 0.0;
    for (int seg = 0; seg < nseg; ++seg) {
        const int inst = inst_index(g, b, seg, gh);
        const float* p = O + (long)inst * 2048 * 64 + d;
        for (int j = rc; j < 2048; j += 4)
            acc += (double)p[(long)j * 64];
    }
    __shared__ double red[256];
    red[t] = acc;
    __syncthreads();
    if (rc == 0) {
        double ssum = red[d] + red[64 + d] + red[128 + d] + red[192 + d];
        sums[(long)blk * 64 + d] = ssum;
    }
}

// -------------------- Pass 3: normalize + dilated scatter --------------------
__global__ __launch_bounds__(256) void out_kernel(
    const float* __restrict__ O, const double* __restrict__ sums,
    float* __restrict__ out)
{
    const int f = blockIdx.x * 256 + threadIdx.x;  // 0 .. 12582911
    const int d  = f & 63;
    const int hh = (f >> 6) % 12;
    const int tk = (f / 768) % 8192;
    const int b  = f / (768 * 8192);

    const int g  = hh >> 2;
    const int gh = hh & 3;
    const int r  = 1 << g;
    const int off = (g == 0) ? 0 : g;

    const int seg = tk >> (11 + g);          // tk / s
    const int pos = tk - (seg << (11 + g));
    const int rem = pos - off;

    float val = 0.f;
    if (rem >= 0 && (rem & (r - 1)) == 0) {
        const int j = rem >> g;
        const int inst = inst_index(g, b, seg, gh);
        float num = O[(long)inst * 131072 + (long)j * 64 + d];
        double den = sums[(long)(g * 8 + b * 4 + gh) * 64 + d] * 3.0;
        val = (float)((double)num / den);
    }
    out[f] = val;
}

extern "C" void kernel_launch(void* const* d_in, const int* in_sizes, int n_in,
                              void* d_out, int out_size, void* d_ws, size_t ws_size,
                              hipStream_t stream) {
    const float* q = (const float*)d_in[0];
    const float* k = (const float*)d_in[1];
    const float* v = (const float*)d_in[2];
    float* out = (float*)d_out;

    double* sums = (double*)d_ws;                       // 1536 doubles
    float*  Ows  = (float*)((char*)d_ws + 16384);       // 56*2048*64 floats = 29.36 MB

    dim3 grid1(32, 56);
    attn_kernel<<<grid1, 256, 0, stream>>>(q, k, v, Ows);
    sum_kernel<<<24, 256, 0, stream>>>(Ows, sums);
    out_kernel<<<49152, 256, 0, stream>>>(Ows, sums, out);
}

// Round 2
// 1152.682 us; speedup vs baseline: 1.4494x; 1.4494x over previous
//
#include <hip/hip_runtime.h>
#include <math.h>

#define TOK_STRIDE 768  // 12 heads * 64 dim, floats per token

__device__ __forceinline__ int inst_index(int g, int b, int seg, int gh) {
    if (g == 0) return b * 16 + seg * 4 + gh;
    if (g == 1) return 32 + b * 8 + seg * 4 + gh;
    return 48 + b * 4 + gh;
}

// -------------------- Pass 1: flash attention per instance --------------------
// grid: (16 row-tiles of 128, 56 instances), block 256, 2 blocks/CU (LDS 80KiB).
// Thread (tx=t&15, ty=t>>4): rows r0=8*ty..+7, keys/dcols c0=4*tx..+3.
// LDS (swizzle s4(i) = ((i>>2)&7)<<2 applied to the fast index, float4-granular):
//   Qt[64][128]  (dd,row) at Qt[dd*128 + (row ^ s4(dd))]      32 KiB
//   U  [64*128]  Kt: (dd,key) at U[dd*64 + (key ^ s4(dd))]    (16 KiB, overwritten)
//                Pt: (key,row) at U[key*128 + (row ^ s4(key))] 32 KiB
//   Vs [64*64]   (key,dd) row-major, unpadded                  16 KiB
__global__ __launch_bounds__(256, 2) void attn_kernel(
    const float* __restrict__ Q, const float* __restrict__ K,
    const float* __restrict__ V, float* __restrict__ O)
{
    const int rt   = blockIdx.x;
    const int inst = blockIdx.y;

    int g, b, seg, gh;
    if (inst < 32)      { g = 0; int x = inst;      b = x >> 4; seg = (x >> 2) & 3; gh = x & 3; }
    else if (inst < 48) { g = 1; int x = inst - 32; b = x >> 3; seg = (x >> 2) & 1; gh = x & 3; }
    else                { g = 2; int x = inst - 48; b = x >> 2; seg = 0;            gh = x & 3; }

    const int  r    = 1 << g;                // dilation 1,2,4
    const int  s    = 2048 << g;             // segment 2048,4096,8192
    const int  off  = (g == 0) ? 0 : g;      // offset 0,1,2
    const int  h    = g * 4 + gh;

    const long tok0  = (long)seg * s + off;
    const long tstep = (long)r * TOK_STRIDE;
    const long base  = ((long)b * 8192 + tok0) * TOK_STRIDE + (long)h * 64;

    const float* qb = Q + base;
    const float* kb = K + base;
    const float* vb = V + base;

    __shared__ float Qt[64 * 128];
    __shared__ float U [64 * 128];
    __shared__ float Vs[64 * 64];

    const int t  = threadIdx.x;
    const int tx = t & 15, ty = t >> 4;
    const int c0 = tx * 4, r0 = ty * 8;

    // ---- stage Q (scaled by softmax scale), transposed + swizzled ----
    #pragma unroll
    for (int p = 0; p < 8; ++p) {
        int flat = p * 256 + t;
        int row  = flat >> 4;
        int dq   = (flat & 15) * 4;
        float4 qv = *(const float4*)(qb + ((long)(rt * 128 + row)) * tstep + dq);
        int col = row ^ (((dq >> 2) & 7) << 2);  // same swizzle for dq..dq+3
        Qt[(dq + 0) * 128 + col] = qv.x * 0.125f;
        Qt[(dq + 1) * 128 + col] = qv.y * 0.125f;
        Qt[(dq + 2) * 128 + col] = qv.z * 0.125f;
        Qt[(dq + 3) * 128 + col] = qv.w * 0.125f;
    }

    float m[8], l[8], o[8][4];
    #pragma unroll
    for (int i = 0; i < 8; ++i) {
        m[i] = -INFINITY; l[i] = 0.f;
        #pragma unroll
        for (int j = 0; j < 4; ++j) o[i][j] = 0.f;
    }

    // register prefetch buffers for K/V staging (4 float4 each)
    float4 kreg[4], vreg[4];
    int    skey[4], sdq[4];
    {
        #pragma unroll
        for (int p = 0; p < 4; ++p) {
            int flat = p * 256 + t;
            skey[p] = flat >> 4;
            sdq[p]  = (flat & 15) * 4;
            const long ofs = ((long)skey[p]) * tstep + sdq[p];
            kreg[p] = *(const float4*)(kb + ofs);
            vreg[p] = *(const float4*)(vb + ofs);
        }
    }

    #pragma unroll 1
    for (int kt = 0; kt < 32; ++kt) {
        // ---- write staged K (transposed+swizzled) and V from registers ----
        #pragma unroll
        for (int p = 0; p < 4; ++p) {
            int key = skey[p], dq = sdq[p];
            int col = key ^ (((dq >> 2) & 7) << 2);
            U[(dq + 0) * 64 + col] = kreg[p].x;
            U[(dq + 1) * 64 + col] = kreg[p].y;
            U[(dq + 2) * 64 + col] = kreg[p].z;
            U[(dq + 3) * 64 + col] = kreg[p].w;
            *(float4*)&Vs[key * 64 + dq] = vreg[p];
        }
        __syncthreads();  // B1: staging visible (also covers Qt on kt=0)

        // issue next tile's global loads early (hide under QK+PV)
        if (kt + 1 < 32) {
            #pragma unroll
            for (int p = 0; p < 4; ++p) {
                const long ofs = ((long)((kt + 1) * 64 + skey[p])) * tstep + sdq[p];
                kreg[p] = *(const float4*)(kb + ofs);
                vreg[p] = *(const float4*)(vb + ofs);
            }
        }

        // ---- QK^T: sc[8 rows][4 keys] ----
        float sc[8][4];
        #pragma unroll
        for (int i = 0; i < 8; ++i)
            #pragma unroll
            for (int j = 0; j < 4; ++j) sc[i][j] = 0.f;

        for (int d4 = 0; d4 < 16; ++d4) {
            const int s4  = (d4 & 7) << 2;
            const int qlo = (d4 * 4) * 128 + (r0 ^ s4);
            const int qhi = (d4 * 4) * 128 + ((r0 + 4) ^ s4);
            const int kof = (d4 * 4) * 64 + (c0 ^ s4);
            #pragma unroll
            for (int j = 0; j < 4; ++j) {
                float4 qa = *(const float4*)&Qt[qlo + j * 128];
                float4 qb4 = *(const float4*)&Qt[qhi + j * 128];
                float4 kf = *(const float4*)&U[kof + j * 64];
                float qv[8] = {qa.x, qa.y, qa.z, qa.w, qb4.x, qb4.y, qb4.z, qb4.w};
                float kv[4] = {kf.x, kf.y, kf.z, kf.w};
                #pragma unroll
                for (int i = 0; i < 8; ++i)
                    #pragma unroll
                    for (int cc = 0; cc < 4; ++cc)
                        sc[i][cc] = fmaf(qv[i], kv[cc], sc[i][cc]);
            }
        }

        // ---- online softmax (reduce across 16-lane tx groups) ----
        float pv[8][4];
        #pragma unroll
        for (int ri = 0; ri < 8; ++ri) {
            float mx = fmaxf(fmaxf(sc[ri][0], sc[ri][1]), fmaxf(sc[ri][2], sc[ri][3]));
            mx = fmaxf(mx, __shfl_xor(mx, 1));
            mx = fmaxf(mx, __shfl_xor(mx, 2));
            mx = fmaxf(mx, __shfl_xor(mx, 4));
            mx = fmaxf(mx, __shfl_xor(mx, 8));
            float mnew = fmaxf(m[ri], mx);
            float f    = __expf(m[ri] - mnew);
            float psum = 0.f;
            #pragma unroll
            for (int ci = 0; ci < 4; ++ci) {
                pv[ri][ci] = __expf(sc[ri][ci] - mnew);
                psum += pv[ri][ci];
            }
            psum += __shfl_xor(psum, 1);
            psum += __shfl_xor(psum, 2);
            psum += __shfl_xor(psum, 4);
            psum += __shfl_xor(psum, 8);
            l[ri] = l[ri] * f + psum;
            m[ri] = mnew;
            #pragma unroll
            for (int ci = 0; ci < 4; ++ci) o[ri][ci] *= f;
        }

        __syncthreads();  // B2: all QK reads of Kt done before Pt overwrite

        // ---- write P transposed+swizzled: Pt[key][row] ----
        {
            const int s4p = (tx & 7) << 2;
            #pragma unroll
            for (int ci = 0; ci < 4; ++ci) {
                const int key = c0 + ci;
                *(float4*)&U[key * 128 + (r0 ^ s4p)] =
                    make_float4(pv[0][ci], pv[1][ci], pv[2][ci], pv[3][ci]);
                *(float4*)&U[key * 128 + ((r0 + 4) ^ s4p)] =
                    make_float4(pv[4][ci], pv[5][ci], pv[6][ci], pv[7][ci]);
            }
        }
        __syncthreads();  // B3: Pt ready

        // ---- O += P^T(rows) * V ----
        for (int k4 = 0; k4 < 16; ++k4) {
            const int s4  = (k4 & 7) << 2;
            const int plo = (k4 * 4) * 128 + (r0 ^ s4);
            const int phi = (k4 * 4) * 128 + ((r0 + 4) ^ s4);
            const int vof = (k4 * 4) * 64 + c0;
            #pragma unroll
            for (int j = 0; j < 4; ++j) {
                float4 pa = *(const float4*)&U[plo + j * 128];
                float4 pb = *(const float4*)&U[phi + j * 128];
                float4 vf = *(const float4*)&Vs[vof + j * 64];
                float pvv[8] = {pa.x, pa.y, pa.z, pa.w, pb.x, pb.y, pb.z, pb.w};
                float vv[4]  = {vf.x, vf.y, vf.z, vf.w};
                #pragma unroll
                for (int i = 0; i < 8; ++i)
                    #pragma unroll
                    for (int cc = 0; cc < 4; ++cc)
                        o[i][cc] = fmaf(pvv[i], vv[cc], o[i][cc]);
            }
        }
        __syncthreads();  // B4: U/Vs consumed; next iter may restage
    }

    // epilogue
    #pragma unroll
    for (int ri = 0; ri < 8; ++ri) {
        float inv = 1.0f / l[ri];
        float4 ov = make_float4(o[ri][0] * inv, o[ri][1] * inv, o[ri][2] * inv, o[ri][3] * inv);
        long row = (long)rt * 128 + r0 + ri;
        *(float4*)(O + ((long)inst * 2048 + row) * 64 + c0) = ov;
    }
}

// -------------------- Pass 2: partial sums (double) --------------------
// grid (24, 16): blk = g*8+b*4+gh, c = row chunk. Thread: d=t&63, rc=t>>6.
__global__ __launch_bounds__(256) void sum_kernel(
    const float* __restrict__ O, double* __restrict__ partial)
{
    const int blk = blockIdx.x;
    const int c   = blockIdx.y;
    const int g   = blk >> 3;
    const int b   = (blk >> 2) & 1;
    const int gh  = blk & 3;
    const int nseg = 4 >> g;
    const int R = nseg << 11;
    const int chunk = R >> 4;

    const int t  = threadIdx.x;
    const int d  = t & 63;
    const int rc = t >> 6;

    double acc = 0.0;
    for (int jr = c * chunk + rc; jr < (c + 1) * chunk; jr += 4) {
        int seg  = jr >> 11;
        int j    = jr & 2047;
        int inst = inst_index(g, b, seg, gh);
        acc += (double)O[(long)inst * 131072 + (long)j * 64 + d];
    }
    __shared__ double red[256];
    red[t] = acc;
    __syncthreads();
    if (rc == 0)
        partial[((long)blk * 16 + c) * 64 + d] =
            red[d] + red[64 + d] + red[128 + d] + red[192 + d];
}

// -------------------- Pass 3: reduce partials -> 1/(3*sum) --------------------
__global__ void inv_kernel(const double* __restrict__ partial, double* __restrict__ invden)
{
    const int blk = blockIdx.x;   // 24
    const int d   = threadIdx.x;  // 64
    double s = 0.0;
    #pragma unroll
    for (int c = 0; c < 16; ++c) s += partial[((long)blk * 16 + c) * 64 + d];
    invden[blk * 64 + d] = 1.0 / (3.0 * s);
}

// -------------------- Pass 4: normalize + dilated scatter --------------------
__global__ __launch_bounds__(256) void out_kernel(
    const float* __restrict__ O, const double* __restrict__ invden,
    float* __restrict__ out)
{
    const int f = blockIdx.x * 256 + threadIdx.x;  // 0 .. 12582911
    const int d  = f & 63;
    const int hh = (f >> 6) % 12;
    const int tk = (f / 768) % 8192;
    const int b  = f / (768 * 8192);

    const int g  = hh >> 2;
    const int gh = hh & 3;
    const int r  = 1 << g;
    const int off = (g == 0) ? 0 : g;

    const int seg = tk >> (11 + g);
    const int pos = tk - (seg << (11 + g));
    const int rem = pos - off;

    float val = 0.f;
    if (rem >= 0 && (rem & (r - 1)) == 0) {
        const int j = rem >> g;
        const int inst = inst_index(g, b, seg, gh);
        float num = O[(long)inst * 131072 + (long)j * 64 + d];
        double iv = invden[(long)(g * 8 + b * 4 + gh) * 64 + d];
        val = (float)((double)num * iv);
    }
    out[f] = val;
}

extern "C" void kernel_launch(void* const* d_in, const int* in_sizes, int n_in,
                              void* d_out, int out_size, void* d_ws, size_t ws_size,
                              hipStream_t stream) {
    const float* q = (const float*)d_in[0];
    const float* k = (const float*)d_in[1];
    const float* v = (const float*)d_in[2];
    float* out = (float*)d_out;

    double* invden  = (double*)d_ws;                         // 24*64*8   = 12288 B
    double* partial = (double*)((char*)d_ws + 12288);        // 24*16*64*8 = 196608 B
    float*  Ows     = (float*)((char*)d_ws + 208896);        // 56*2048*64*4 = 29.36 MB

    dim3 grid1(16, 56);
    attn_kernel<<<grid1, 256, 0, stream>>>(q, k, v, Ows);
    dim3 grid2(24, 16);
    sum_kernel<<<grid2, 256, 0, stream>>>(Ows, partial);
    inv_kernel<<<24, 64, 0, stream>>>(partial, invden);
    out_kernel<<<49152, 256, 0, stream>>>(Ows, invden, out);
}

// Round 4
// 406.253 us; speedup vs baseline: 4.1124x; 2.8373x over previous
//
#include <hip/hip_runtime.h>
#include <math.h>

#define TOK_STRIDE 768  // 12 heads * 64 dim, floats per token

typedef __attribute__((ext_vector_type(8))) _Float16 f16x8;
typedef __attribute__((ext_vector_type(16))) float f32x16;

__device__ __forceinline__ int inst_index(int g, int b, int seg, int gh) {
    if (g == 0) return b * 16 + seg * 4 + gh;
    if (g == 1) return 32 + b * 8 + seg * 4 + gh;
    return 48 + b * 4 + gh;
}

__device__ __forceinline__ void decode_inst(int inst, int& g, int& b, int& seg, int& gh) {
    if (inst < 32)      { g = 0; int x = inst;      b = x >> 4; seg = (x >> 2) & 3; gh = x & 3; }
    else if (inst < 48) { g = 1; int x = inst - 32; b = x >> 3; seg = (x >> 2) & 1; gh = x & 3; }
    else                { g = 2; int x = inst - 48; b = x >> 2; seg = 0;            gh = x & 3; }
}

__device__ __forceinline__ long inst_base(int g, int b, int seg, int gh, long& tstep) {
    int r = 1 << g, s = 2048 << g, off = (g == 0) ? 0 : g, h = g * 4 + gh;
    tstep = (long)r * TOK_STRIDE;
    long tok0 = (long)seg * s + off;
    return ((long)b * 8192 + tok0) * TOK_STRIDE + (long)h * 64;
}

// fp16 split: x ~= hi + lo, each RNE fp16 (11+11 significand bits)
__device__ __forceinline__ void h_split(float x, unsigned short& hi, unsigned short& lo) {
    _Float16 h = (_Float16)x;
    _Float16 l = (_Float16)(x - (float)h);
    hi = __builtin_bit_cast(unsigned short, h);
    lo = __builtin_bit_cast(unsigned short, l);
}

// pack two floats to fp16 RNE pair (low half = a)
__device__ __forceinline__ unsigned h2_rn(float a, float b) {
    unsigned short ua = __builtin_bit_cast(unsigned short, (_Float16)a);
    unsigned short ub = __builtin_bit_cast(unsigned short, (_Float16)b);
    return (unsigned)ua | ((unsigned)ub << 16);
}

__device__ __forceinline__ void gload_lds16(void* lds, const void* g) {
    __builtin_amdgcn_global_load_lds(
        (const __attribute__((address_space(1))) unsigned int*)g,
        (__attribute__((address_space(3))) unsigned int*)lds, 16, 0, 0);
}

// ============ Pass 0: convert K,V to split-fp16 fragment-major layouts ============
// Kh/Kl[inst] : [kt 0..31][dc 0..3][h 0..1][key 0..63][8]   (8 KB per tile)
// Vth/Vtl[inst]: [kc 0..127][h 0..1][d 0..63][8]            (tile = 4 kc = 8 KB)
__global__ __launch_bounds__(256) void prep_kernel(
    const float* __restrict__ K, const float* __restrict__ V,
    unsigned short* __restrict__ Kh, unsigned short* __restrict__ Kl,
    unsigned short* __restrict__ Vth, unsigned short* __restrict__ Vtl)
{
    const int kt = blockIdx.x, inst = blockIdx.y;
    int g, b, seg, gh; decode_inst(inst, g, b, seg, gh);
    long tstep; const long base = inst_base(g, b, seg, gh, tstep);
    const float* kb = K + base;
    const float* vb = V + base;
    const int t = threadIdx.x;

    __shared__ float Vs[64][72];

    #pragma unroll
    for (int p = 0; p < 4; ++p) {
        int flat = p * 256 + t;
        int key = flat >> 4;
        int d0 = (flat & 15) * 4;
        const long src = ((long)(kt * 64 + key)) * tstep + d0;
        float4 xk = *(const float4*)(kb + src);
        float kvals[4] = {xk.x, xk.y, xk.z, xk.w};
        unsigned short hi[4], lo[4];
        #pragma unroll
        for (int e = 0; e < 4; ++e) h_split(kvals[e], hi[e], lo[e]);
        int dc = d0 >> 4, hh = (d0 >> 3) & 1, j = d0 & 7;
        long idx = ((((long)inst * 32 + kt) * 8 + dc * 2 + hh) * 64 + key) * 8 + j;
        *(ushort4*)(Kh + idx) = make_ushort4(hi[0], hi[1], hi[2], hi[3]);
        *(ushort4*)(Kl + idx) = make_ushort4(lo[0], lo[1], lo[2], lo[3]);
        float4 xv = *(const float4*)(vb + src);
        float vvals[4] = {xv.x, xv.y, xv.z, xv.w};
        #pragma unroll
        for (int e = 0; e < 4; ++e) {
            int d = d0 + e;
            Vs[d][key ^ ((((d) >> 2) & 7) << 3)] = vvals[e];
        }
    }
    __syncthreads();
    #pragma unroll
    for (int p = 0; p < 4; ++p) {
        int flat = p * 256 + t;
        int d = flat >> 4;
        int k40 = (flat & 15) * 4;
        int swz = ((d >> 2) & 7) << 3;
        float4 xv = *(const float4*)&Vs[d][k40 ^ swz];
        float vvals[4] = {xv.x, xv.y, xv.z, xv.w};
        unsigned short hi[4], lo[4];
        #pragma unroll
        for (int e = 0; e < 4; ++e) h_split(vvals[e], hi[e], lo[e]);
        int k = kt * 64 + k40;
        int kc = k >> 4, hh = (k >> 3) & 1, j = k & 7;
        long idx = ((((long)inst * 128 + kc) * 2 + hh) * 64 + d) * 8 + j;
        *(ushort4*)(Vth + idx) = make_ushort4(hi[0], hi[1], hi[2], hi[3]);
        *(ushort4*)(Vtl + idx) = make_ushort4(lo[0], lo[1], lo[2], lo[3]);
    }
}

// ============ Pass 1: MFMA flash attention (split-fp16 emulated fp32) ============
// grid (16, 56), 256 threads = 4 waves; wave w owns rows rt*128 + w*32 .. +31.
// LDS: KVb[2 bufs][Kh|Kl|Vth|Vtl, 4096 ushorts each]; Pb[wave][4 KB].
__global__ __launch_bounds__(256, 2) void attn_kernel(
    const float* __restrict__ Q,
    const unsigned short* __restrict__ Kh, const unsigned short* __restrict__ Kl,
    const unsigned short* __restrict__ Vth, const unsigned short* __restrict__ Vtl,
    float* __restrict__ O)
{
    const int rt = blockIdx.x, inst = blockIdx.y;
    int g, b, seg, gh; decode_inst(inst, g, b, seg, gh);
    long tstep; const long base = inst_base(g, b, seg, gh, tstep);
    const float* qb = Q + base;

    __shared__ unsigned short KVb[2][16384];
    __shared__ unsigned short Pb[4][2048];

    const int t = threadIdx.x;
    const int lane = t & 63;
    const int w = t >> 6;
    const int l31 = lane & 31;
    const int h = lane >> 5;

    // ---- Q fragments (scaled by 0.125, split hi/lo fp16) ----
    const float* qp = qb + (long)(rt * 128 + w * 32 + l31) * tstep;
    f16x8 Qhf[4], Qlf[4];
    #pragma unroll
    for (int dc = 0; dc < 4; ++dc) {
        float4 f0 = *(const float4*)(qp + dc * 16 + h * 8);
        float4 f1 = *(const float4*)(qp + dc * 16 + h * 8 + 4);
        float vals[8] = {f0.x, f0.y, f0.z, f0.w, f1.x, f1.y, f1.z, f1.w};
        #pragma unroll
        for (int j = 0; j < 8; ++j) {
            float x = vals[j] * 0.125f;
            _Float16 hi = (_Float16)x;
            _Float16 lo = (_Float16)(x - (float)hi);
            Qhf[dc][j] = hi;
            Qlf[dc][j] = lo;
        }
    }

    // ---- stage tile 0 into buf 0 (wave w stages one of the 4 arrays) ----
    const unsigned short* sbase = (w == 0) ? Kh : (w == 1) ? Kl : (w == 2) ? Vth : Vtl;
    const unsigned short* sp0 = sbase + (long)inst * 131072;
    #pragma unroll
    for (int i = 0; i < 8; ++i)
        gload_lds16(&KVb[0][w * 4096 + i * 512], sp0 + i * 512 + lane * 8);

    f32x16 o0, o1;
    #pragma unroll
    for (int rr = 0; rr < 16; ++rr) { o0[rr] = 0.f; o1[rr] = 0.f; }
    float m = -INFINITY, lsum = 0.f;

    __syncthreads();

    for (int kt = 0; kt < 32; ++kt) {
        const int cb = kt & 1;
        if (kt + 1 < 32) {
            const unsigned short* sp = sp0 + (long)(kt + 1) * 4096;
            #pragma unroll
            for (int i = 0; i < 8; ++i)
                gload_lds16(&KVb[cb ^ 1][w * 4096 + i * 512], sp + i * 512 + lane * 8);
        }

        // ---- QK^T (swapped): sS = K_tile . Q^T, rows=keys cols=q ----
        f32x16 sS[2];
        #pragma unroll
        for (int a = 0; a < 2; ++a)
            #pragma unroll
            for (int rr = 0; rr < 16; ++rr) sS[a][rr] = 0.f;

        #pragma unroll
        for (int dc = 0; dc < 4; ++dc) {
            #pragma unroll
            for (int kt2 = 0; kt2 < 2; ++kt2) {
                int aoff = ((dc * 2 + h) * 64 + kt2 * 32 + l31) * 8;
                f16x8 kh = *(const f16x8*)&KVb[cb][aoff];
                f16x8 kl = *(const f16x8*)&KVb[cb][4096 + aoff];
                sS[kt2] = __builtin_amdgcn_mfma_f32_32x32x16_f16(kh, Qhf[dc], sS[kt2], 0, 0, 0);
                sS[kt2] = __builtin_amdgcn_mfma_f32_32x32x16_f16(kh, Qlf[dc], sS[kt2], 0, 0, 0);
                sS[kt2] = __builtin_amdgcn_mfma_f32_32x32x16_f16(kl, Qhf[dc], sS[kt2], 0, 0, 0);
            }
        }

        // ---- online softmax (lane-local rows; pair-exchange via shfl_xor 32) ----
        float pmax = -INFINITY;
        #pragma unroll
        for (int a = 0; a < 2; ++a)
            #pragma unroll
            for (int rr = 0; rr < 16; ++rr) pmax = fmaxf(pmax, sS[a][rr]);
        pmax = fmaxf(pmax, __shfl_xor(pmax, 32));

        if (!__all(pmax <= m + 8.f)) {   // defer-max THR=8
            float mnew = fmaxf(m, pmax);
            float f = __expf(m - mnew);
            m = mnew;
            lsum *= f;
            #pragma unroll
            for (int rr = 0; rr < 16; ++rr) { o0[rr] *= f; o1[rr] *= f; }
        }
        float psum = 0.f;
        #pragma unroll
        for (int a = 0; a < 2; ++a)
            #pragma unroll
            for (int rr = 0; rr < 16; ++rr) {
                float p = __expf(sS[a][rr] - m);
                sS[a][rr] = p;
                psum += p;
            }
        psum += __shfl_xor(psum, 32);
        lsum += psum;

        // ---- pack P to fp16 RNE, write to Pb[w] in B-fragment layout ----
        #pragma unroll
        for (int kt2 = 0; kt2 < 2; ++kt2) {
            #pragma unroll
            for (int qd = 0; qd < 4; ++qd) {
                unsigned w0 = h2_rn(sS[kt2][qd * 4 + 0], sS[kt2][qd * 4 + 1]);
                unsigned w1 = h2_rn(sS[kt2][qd * 4 + 2], sS[kt2][qd * 4 + 3]);
                int k = kt2 * 32 + qd * 8 + 4 * h;
                int kc = k >> 4, hh = (k >> 3) & 1, j = k & 7;
                int idx = ((kc * 2 + hh) * 32 + l31) * 8 + j;
                *(uint2*)&Pb[w][idx] = make_uint2(w0, w1);
            }
        }

        // ---- PV: o += Vt_tile . P^T  (A=Vt hi/lo, B=Ph) ----
        #pragma unroll
        for (int kc = 0; kc < 4; ++kc) {
            f16x8 pf = *(const f16x8*)&Pb[w][((kc * 2 + h) * 32 + l31) * 8];
            int voff = ((kc * 2 + h) * 64 + l31) * 8;
            f16x8 vh0 = *(const f16x8*)&KVb[cb][8192 + voff];
            f16x8 vl0 = *(const f16x8*)&KVb[cb][12288 + voff];
            f16x8 vh1 = *(const f16x8*)&KVb[cb][8192 + voff + 256];
            f16x8 vl1 = *(const f16x8*)&KVb[cb][12288 + voff + 256];
            o0 = __builtin_amdgcn_mfma_f32_32x32x16_f16(vh0, pf, o0, 0, 0, 0);
            o0 = __builtin_amdgcn_mfma_f32_32x32x16_f16(vl0, pf, o0, 0, 0, 0);
            o1 = __builtin_amdgcn_mfma_f32_32x32x16_f16(vh1, pf, o1, 0, 0, 0);
            o1 = __builtin_amdgcn_mfma_f32_32x32x16_f16(vl1, pf, o1, 0, 0, 0);
        }

        __syncthreads();  // drains vmcnt(0): next buf staged; all reads of cb done
    }

    // ---- epilogue: O^T regs -> Ows[inst][q][d], scaled by 1/lsum ----
    float inv = 1.0f / lsum;
    const int q = rt * 128 + w * 32 + l31;
    float* op = O + ((long)inst * 2048 + q) * 64;
    #pragma unroll
    for (int c = 0; c < 4; ++c) {
        int d0 = c * 8 + 4 * h;
        *(float4*)(op + d0) = make_float4(o0[c * 4] * inv, o0[c * 4 + 1] * inv,
                                          o0[c * 4 + 2] * inv, o0[c * 4 + 3] * inv);
        *(float4*)(op + 32 + d0) = make_float4(o1[c * 4] * inv, o1[c * 4 + 1] * inv,
                                               o1[c * 4 + 2] * inv, o1[c * 4 + 3] * inv);
    }
}

// ============ Pass 2: partial sums (double) ============
__global__ __launch_bounds__(256) void sum_kernel(
    const float* __restrict__ O, double* __restrict__ partial)
{
    const int blk = blockIdx.x;
    const int c   = blockIdx.y;
    const int g   = blk >> 3;
    const int b   = (blk >> 2) & 1;
    const int gh  = blk & 3;
    const int nseg = 4 >> g;
    const int R = nseg << 11;
    const int chunk = R >> 4;

    const int t  = threadIdx.x;
    const int d  = t & 63;
    const int rc = t >> 6;

    double acc = 0.0;
    for (int jr = c * chunk + rc; jr < (c + 1) * chunk; jr += 4) {
        int seg  = jr >> 11;
        int j    = jr & 2047;
        int inst = inst_index(g, b, seg, gh);
        acc += (double)O[(long)inst * 131072 + (long)j * 64 + d];
    }
    __shared__ double red[256];
    red[t] = acc;
    __syncthreads();
    if (rc == 0)
        partial[((long)blk * 16 + c) * 64 + d] =
            red[d] + red[64 + d] + red[128 + d] + red[192 + d];
}

// ============ Pass 3: reduce partials -> 1/(3*sum) ============
__global__ void inv_kernel(const double* __restrict__ partial, double* __restrict__ invden)
{
    const int blk = blockIdx.x;   // 24
    const int d   = threadIdx.x;  // 64
    double s = 0.0;
    #pragma unroll
    for (int c = 0; c < 16; ++c) s += partial[((long)blk * 16 + c) * 64 + d];
    invden[blk * 64 + d] = 1.0 / (3.0 * s);
}

// ============ Pass 4: normalize + dilated scatter ============
__global__ __launch_bounds__(256) void out_kernel(
    const float* __restrict__ O, const double* __restrict__ invden,
    float* __restrict__ out)
{
    const int f = blockIdx.x * 256 + threadIdx.x;  // 0 .. 12582911
    const int d  = f & 63;
    const int hh = (f >> 6) % 12;
    const int tk = (f / 768) % 8192;
    const int b  = f / (768 * 8192);

    const int g  = hh >> 2;
    const int gh = hh & 3;
    const int r  = 1 << g;
    const int off = (g == 0) ? 0 : g;

    const int seg = tk >> (11 + g);
    const int pos = tk - (seg << (11 + g));
    const int rem = pos - off;

    float val = 0.f;
    if (rem >= 0 && (rem & (r - 1)) == 0) {
        const int j = rem >> g;
        const int inst = inst_index(g, b, seg, gh);
        float num = O[(long)inst * 131072 + (long)j * 64 + d];
        double iv = invden[(long)(g * 8 + b * 4 + gh) * 64 + d];
        val = (float)((double)num * iv);
    }
    out[f] = val;
}

extern "C" void kernel_launch(void* const* d_in, const int* in_sizes, int n_in,
                              void* d_out, int out_size, void* d_ws, size_t ws_size,
                              hipStream_t stream) {
    const float* q = (const float*)d_in[0];
    const float* k = (const float*)d_in[1];
    const float* v = (const float*)d_in[2];
    float* out = (float*)d_out;

    char* ws = (char*)d_ws;
    double* invden  = (double*)(ws);                       // 12,288 B
    double* partial = (double*)(ws + 12288);               // 196,608 B
    float*  Ows     = (float*)(ws + 208896);               // 29,360,128 B
    unsigned short* Khp  = (unsigned short*)(ws + 29569024);   // 14,680,064 B each
    unsigned short* Klp  = (unsigned short*)(ws + 44249088);
    unsigned short* Vthp = (unsigned short*)(ws + 58929152);
    unsigned short* Vtlp = (unsigned short*)(ws + 73609216);
    // total: 88,289,280 B

    dim3 gprep(32, 56);
    prep_kernel<<<gprep, 256, 0, stream>>>(k, v, Khp, Klp, Vthp, Vtlp);
    dim3 gattn(16, 56);
    attn_kernel<<<gattn, 256, 0, stream>>>(q, Khp, Klp, Vthp, Vtlp, Ows);
    dim3 gsum(24, 16);
    sum_kernel<<<gsum, 256, 0, stream>>>(Ows, partial);
    inv_kernel<<<24, 64, 0, stream>>>(partial, invden);
    out_kernel<<<49152, 256, 0, stream>>>(Ows, invden, out);
}

// Round 5
// 398.122 us; speedup vs baseline: 4.1964x; 1.0204x over previous
//
#include <hip/hip_runtime.h>
#include <math.h>

#define TOK_STRIDE 768  // 12 heads * 64 dim, floats per token

typedef __attribute__((ext_vector_type(8))) _Float16 f16x8;
typedef __attribute__((ext_vector_type(16))) float f32x16;
typedef __attribute__((ext_vector_type(4))) unsigned uint4v;

__device__ __forceinline__ int inst_index(int g, int b, int seg, int gh) {
    if (g == 0) return b * 16 + seg * 4 + gh;
    if (g == 1) return 32 + b * 8 + seg * 4 + gh;
    return 48 + b * 4 + gh;
}

__device__ __forceinline__ void decode_inst(int inst, int& g, int& b, int& seg, int& gh) {
    if (inst < 32)      { g = 0; int x = inst;      b = x >> 4; seg = (x >> 2) & 3; gh = x & 3; }
    else if (inst < 48) { g = 1; int x = inst - 32; b = x >> 3; seg = (x >> 2) & 1; gh = x & 3; }
    else                { g = 2; int x = inst - 48; b = x >> 2; seg = 0;            gh = x & 3; }
}

__device__ __forceinline__ long inst_base(int g, int b, int seg, int gh, long& tstep) {
    int r = 1 << g, s = 2048 << g, off = (g == 0) ? 0 : g, h = g * 4 + gh;
    tstep = (long)r * TOK_STRIDE;
    long tok0 = (long)seg * s + off;
    return ((long)b * 8192 + tok0) * TOK_STRIDE + (long)h * 64;
}

// fp16 split: x ~= hi + lo, each RNE fp16
__device__ __forceinline__ void h_split(float x, unsigned short& hi, unsigned short& lo) {
    _Float16 h = (_Float16)x;
    _Float16 l = (_Float16)(x - (float)h);
    hi = __builtin_bit_cast(unsigned short, h);
    lo = __builtin_bit_cast(unsigned short, l);
}

__device__ __forceinline__ unsigned h2_rn(float a, float b) {
    unsigned short ua = __builtin_bit_cast(unsigned short, (_Float16)a);
    unsigned short ub = __builtin_bit_cast(unsigned short, (_Float16)b);
    return (unsigned)ua | ((unsigned)ub << 16);
}

__device__ __forceinline__ void gload_lds16(void* lds, const void* g) {
    __builtin_amdgcn_global_load_lds(
        (const __attribute__((address_space(1))) unsigned int*)g,
        (__attribute__((address_space(3))) unsigned int*)lds, 16, 0, 0);
}

__device__ __forceinline__ uint4v split8(float4 a, float4 b, uint4v& lo4) {
    float v[8] = {a.x, a.y, a.z, a.w, b.x, b.y, b.z, b.w};
    unsigned short hi[8], lo[8];
    #pragma unroll
    for (int e = 0; e < 8; ++e) h_split(v[e], hi[e], lo[e]);
    uint4v h4, l4;
    #pragma unroll
    for (int wdi = 0; wdi < 4; ++wdi) {
        h4[wdi] = (unsigned)hi[2 * wdi] | ((unsigned)hi[2 * wdi + 1] << 16);
        l4[wdi] = (unsigned)lo[2 * wdi] | ((unsigned)lo[2 * wdi + 1] << 16);
    }
    lo4 = l4;
    return h4;
}

// ============ Pass 0: convert K,V to split-fp16 fragment-major layouts ============
// Kh/Kl[inst] : [kt 0..31][dg 0..7][key 0..63][8]   (dg = dc*2+hh; 8 KB per tile)
// Vth/Vtl[inst]: [kc 0..127][hh 0..1][d 0..63][8]   (tile = 4 kc = 8 KB)
__global__ __launch_bounds__(256) void prep_kernel(
    const float* __restrict__ K, const float* __restrict__ V,
    unsigned short* __restrict__ Kh, unsigned short* __restrict__ Kl,
    unsigned short* __restrict__ Vth, unsigned short* __restrict__ Vtl)
{
    const int kt = blockIdx.x, inst = blockIdx.y;
    int g, b, seg, gh; decode_inst(inst, g, b, seg, gh);
    long tstep; const long base = inst_base(g, b, seg, gh, tstep);
    const float* kb = K + base;
    const float* vb = V + base;
    const int t = threadIdx.x;

    __shared__ float Vs[64][72];

    #pragma unroll
    for (int p = 0; p < 2; ++p) {
        int item = p * 256 + t;
        int key = item >> 3, dg = item & 7, d0 = dg * 8;
        long src = (long)(kt * 64 + key) * tstep + d0;
        float4 ka  = *(const float4*)(kb + src);
        float4 ka2 = *(const float4*)(kb + src + 4);
        uint4v lo4;
        uint4v hi4 = split8(ka, ka2, lo4);
        long idx = ((((long)inst * 32 + kt) * 8 + dg) * 64 + key) * 8;
        *(uint4v*)(Kh + idx) = hi4;
        *(uint4v*)(Kl + idx) = lo4;
        float4 va  = *(const float4*)(vb + src);
        float4 va2 = *(const float4*)(vb + src + 4);
        float vv[8] = {va.x, va.y, va.z, va.w, va2.x, va2.y, va2.z, va2.w};
        #pragma unroll
        for (int e = 0; e < 8; ++e) {
            int d = d0 + e;
            Vs[d][key ^ (((d >> 2) & 7) << 3)] = vv[e];
        }
    }
    __syncthreads();
    #pragma unroll
    for (int p = 0; p < 2; ++p) {
        int item = p * 256 + t;
        int d = item >> 3, kg = item & 7, k0 = kg * 8;
        int swz = ((d >> 2) & 7) << 3;
        float4 x0 = *(const float4*)&Vs[d][k0 ^ swz];
        float4 x1 = *(const float4*)&Vs[d][(k0 + 4) ^ swz];
        uint4v lo4;
        uint4v hi4 = split8(x0, x1, lo4);
        long idx = ((((long)inst * 128 + kt * 4 + (kg >> 1)) * 2 + (kg & 1)) * 64 + d) * 8;
        *(uint4v*)(Vth + idx) = hi4;
        *(uint4v*)(Vtl + idx) = lo4;
    }
}

// ============ Pass 1: MFMA flash attention (split-fp16 emulated fp32) ============
// 1-D grid 896: inst = bx%56 (co-locates an instance's 16 blocks on one XCD), rt = bx/56.
// 4 waves; wave w owns q-rows rt*128 + w*32 .. +31.
// LDS 48 KiB: Kb[2][8192]us (Kh|Kl per buf), Vb[8192]us (Vth|Vtl). 3 blocks/CU.
__global__ __launch_bounds__(256, 3) void attn_kernel(
    const float* __restrict__ Q,
    const unsigned short* __restrict__ Kh, const unsigned short* __restrict__ Kl,
    const unsigned short* __restrict__ Vth, const unsigned short* __restrict__ Vtl,
    float* __restrict__ O)
{
    const int bx = blockIdx.x;
    const int inst = bx % 56;
    const int rt   = bx / 56;
    int g, b, seg, gh; decode_inst(inst, g, b, seg, gh);
    long tstep; const long base = inst_base(g, b, seg, gh, tstep);
    const float* qb = Q + base;

    __shared__ unsigned short Kb[2][8192];
    __shared__ unsigned short Vb[8192];

    const int t = threadIdx.x;
    const int lane = t & 63;
    const int w = t >> 6;
    const int l31 = lane & 31;
    const int h = lane >> 5;

    // ---- Q fragments (scaled by 0.125, split hi/lo fp16) ----
    const float* qp = qb + (long)(rt * 128 + w * 32 + l31) * tstep;
    f16x8 Qhf[4], Qlf[4];
    #pragma unroll
    for (int dc = 0; dc < 4; ++dc) {
        float4 f0 = *(const float4*)(qp + dc * 16 + h * 8);
        float4 f1 = *(const float4*)(qp + dc * 16 + h * 8 + 4);
        float vals[8] = {f0.x, f0.y, f0.z, f0.w, f1.x, f1.y, f1.z, f1.w};
        #pragma unroll
        for (int j = 0; j < 8; ++j) {
            float x = vals[j] * 0.125f;
            _Float16 hi = (_Float16)x;
            _Float16 lo = (_Float16)(x - (float)hi);
            Qhf[dc][j] = hi;
            Qlf[dc][j] = lo;
        }
    }

    // staging: 16 K-segments (Kh 0-7, Kl 8-15) and 16 V-segments per tile; wave w does 4 of each
    const unsigned short* KsA = Kh  + (long)inst * 131072;
    const unsigned short* KsB = Kl  + (long)inst * 131072;
    const unsigned short* VsA = Vth + (long)inst * 131072;
    const unsigned short* VsB = Vtl + (long)inst * 131072;
    const int s0 = w * 4;

    // stage K tile 0 into buf 0
    #pragma unroll
    for (int i = 0; i < 4; ++i) {
        int s = s0 + i;
        const unsigned short* src = ((s < 8) ? KsA : KsB) + (s & 7) * 512 + lane * 8;
        gload_lds16(&Kb[0][s * 512], src);
    }

    f32x16 o0, o1;
    #pragma unroll
    for (int rr = 0; rr < 16; ++rr) { o0[rr] = 0.f; o1[rr] = 0.f; }
    float m = -INFINITY, lsum = 0.f;

    __syncthreads();

    #pragma unroll 1
    for (int kt = 0; kt < 32; ++kt) {
        const int cb = kt & 1;

        // ---- issue V[kt] loads (4), then K[kt+1] loads (4); order pinned ----
        #pragma unroll
        for (int i = 0; i < 4; ++i) {
            int s = s0 + i;
            const unsigned short* src = ((s < 8) ? VsA : VsB) + (long)kt * 4096 + (s & 7) * 512 + lane * 8;
            gload_lds16(&Vb[s * 512], src);
        }
        asm volatile("" ::: "memory");
        if (kt + 1 < 32) {
            #pragma unroll
            for (int i = 0; i < 4; ++i) {
                int s = s0 + i;
                const unsigned short* src = ((s < 8) ? KsA : KsB) + (long)(kt + 1) * 4096 + (s & 7) * 512 + lane * 8;
                gload_lds16(&Kb[cb ^ 1][s * 512], src);
            }
        }
        asm volatile("" ::: "memory");

        // ---- QK^T (swapped): sS = K_tile . Q^T, rows=keys cols=q ----
        f32x16 sS[2];
        #pragma unroll
        for (int a = 0; a < 2; ++a)
            #pragma unroll
            for (int rr = 0; rr < 16; ++rr) sS[a][rr] = 0.f;

        __builtin_amdgcn_s_setprio(1);
        #pragma unroll
        for (int dc = 0; dc < 4; ++dc) {
            #pragma unroll
            for (int kt2 = 0; kt2 < 2; ++kt2) {
                int aoff = ((dc * 2 + h) * 64 + kt2 * 32 + l31) * 8;
                f16x8 kh = *(const f16x8*)&Kb[cb][aoff];
                f16x8 kl = *(const f16x8*)&Kb[cb][4096 + aoff];
                sS[kt2] = __builtin_amdgcn_mfma_f32_32x32x16_f16(kh, Qhf[dc], sS[kt2], 0, 0, 0);
                sS[kt2] = __builtin_amdgcn_mfma_f32_32x32x16_f16(kh, Qlf[dc], sS[kt2], 0, 0, 0);
                sS[kt2] = __builtin_amdgcn_mfma_f32_32x32x16_f16(kl, Qhf[dc], sS[kt2], 0, 0, 0);
            }
        }
        __builtin_amdgcn_s_setprio(0);

        // ---- online softmax (lane-local rows; pair-exchange via shfl_xor 32) ----
        float pmax = -INFINITY;
        #pragma unroll
        for (int a = 0; a < 2; ++a)
            #pragma unroll
            for (int rr = 0; rr < 16; ++rr) pmax = fmaxf(pmax, sS[a][rr]);
        pmax = fmaxf(pmax, __shfl_xor(pmax, 32));

        if (!__all(pmax <= m + 8.f)) {   // defer-max THR=8
            float mnew = fmaxf(m, pmax);
            float f = __expf(m - mnew);
            m = mnew;
            lsum *= f;
            #pragma unroll
            for (int rr = 0; rr < 16; ++rr) { o0[rr] *= f; o1[rr] *= f; }
        }
        float psum = 0.f;
        #pragma unroll
        for (int a = 0; a < 2; ++a)
            #pragma unroll
            for (int rr = 0; rr < 16; ++rr) {
                float p = __expf(sS[a][rr] - m);
                sS[a][rr] = p;
                psum += p;
            }
        psum += __shfl_xor(psum, 32);
        lsum += psum;

        // ---- pack P to fp16 pairs (in-register) ----
        unsigned pw[2][4][2];
        #pragma unroll
        for (int kt2 = 0; kt2 < 2; ++kt2)
            #pragma unroll
            for (int qd = 0; qd < 4; ++qd) {
                pw[kt2][qd][0] = h2_rn(sS[kt2][qd * 4 + 0], sS[kt2][qd * 4 + 1]);
                pw[kt2][qd][1] = h2_rn(sS[kt2][qd * 4 + 2], sS[kt2][qd * 4 + 3]);
            }

        // ---- wait V staged (K prefetch stays in flight), join waves ----
        if (kt + 1 < 32) { asm volatile("s_waitcnt vmcnt(4)" ::: "memory"); }
        else             { asm volatile("s_waitcnt vmcnt(0)" ::: "memory"); }
        __builtin_amdgcn_s_barrier();
        asm volatile("" ::: "memory");

        // ---- PV: o += Vt_tile . P^T; B-frag via half-exchange ----
        __builtin_amdgcn_s_setprio(1);
        #pragma unroll
        for (int kc = 0; kc < 4; ++kc) {
            const int kt2 = kc >> 1, q0 = (kc & 1) * 2;
            unsigned a0 = pw[kt2][q0][0],     a1 = pw[kt2][q0][1];
            unsigned b0 = pw[kt2][q0 + 1][0], b1 = pw[kt2][q0 + 1][1];
            unsigned oa0 = __shfl_xor(a0, 32), oa1 = __shfl_xor(a1, 32);
            unsigned ob0 = __shfl_xor(b0, 32), ob1 = __shfl_xor(b1, 32);
            uint4v u;
            u[0] = h ? ob0 : a0;   // keys j=0,1 (from h_src=0 lane)
            u[1] = h ? ob1 : a1;   // keys j=2,3
            u[2] = h ? b0  : oa0;  // keys j=4,5 (from h_src=1 lane)
            u[3] = h ? b1  : oa1;  // keys j=6,7
            f16x8 pf = __builtin_bit_cast(f16x8, u);
            int voff = ((kc * 2 + h) * 64 + l31) * 8;
            f16x8 vh0 = *(const f16x8*)&Vb[voff];
            f16x8 vl0 = *(const f16x8*)&Vb[4096 + voff];
            f16x8 vh1 = *(const f16x8*)&Vb[voff + 256];
            f16x8 vl1 = *(const f16x8*)&Vb[4096 + voff + 256];
            o0 = __builtin_amdgcn_mfma_f32_32x32x16_f16(vh0, pf, o0, 0, 0, 0);
            o0 = __builtin_amdgcn_mfma_f32_32x32x16_f16(vl0, pf, o0, 0, 0, 0);
            o1 = __builtin_amdgcn_mfma_f32_32x32x16_f16(vh1, pf, o1, 0, 0, 0);
            o1 = __builtin_amdgcn_mfma_f32_32x32x16_f16(vl1, pf, o1, 0, 0, 0);
        }
        __builtin_amdgcn_s_setprio(0);

        __syncthreads();  // drains vmcnt(0): K[kt+1] staged; Vb reads retired
    }

    // ---- epilogue: regs -> Ows[inst][q][d], scaled by 1/lsum ----
    float inv = 1.0f / lsum;
    const int q = rt * 128 + w * 32 + l31;
    float* op = O + ((long)inst * 2048 + q) * 64;
    #pragma unroll
    for (int c = 0; c < 4; ++c) {
        int d0 = c * 8 + 4 * h;
        *(float4*)(op + d0) = make_float4(o0[c * 4] * inv, o0[c * 4 + 1] * inv,
                                          o0[c * 4 + 2] * inv, o0[c * 4 + 3] * inv);
        *(float4*)(op + 32 + d0) = make_float4(o1[c * 4] * inv, o1[c * 4 + 1] * inv,
                                               o1[c * 4 + 2] * inv, o1[c * 4 + 3] * inv);
    }
}

// ============ Pass 2: partial sums (double) ============
__global__ __launch_bounds__(256) void sum_kernel(
    const float* __restrict__ O, double* __restrict__ partial)
{
    const int blk = blockIdx.x;
    const int c   = blockIdx.y;
    const int g   = blk >> 3;
    const int b   = (blk >> 2) & 1;
    const int gh  = blk & 3;
    const int nseg = 4 >> g;
    const int R = nseg << 11;
    const int chunk = R >> 4;

    const int t  = threadIdx.x;
    const int d  = t & 63;
    const int rc = t >> 6;

    double acc = 0.0;
    for (int jr = c * chunk + rc; jr < (c + 1) * chunk; jr += 4) {
        int seg  = jr >> 11;
        int j    = jr & 2047;
        int inst = inst_index(g, b, seg, gh);
        acc += (double)O[(long)inst * 131072 + (long)j * 64 + d];
    }
    __shared__ double red[256];
    red[t] = acc;
    __syncthreads();
    if (rc == 0)
        partial[((long)blk * 16 + c) * 64 + d] =
            red[d] + red[64 + d] + red[128 + d] + red[192 + d];
}

// ============ Pass 3: reduce partials -> 1/(3*sum) ============
__global__ void inv_kernel(const double* __restrict__ partial, double* __restrict__ invden)
{
    const int blk = blockIdx.x;   // 24
    const int d   = threadIdx.x;  // 64
    double s = 0.0;
    #pragma unroll
    for (int c = 0; c < 16; ++c) s += partial[((long)blk * 16 + c) * 64 + d];
    invden[blk * 64 + d] = 1.0 / (3.0 * s);
}

// ============ Pass 4: normalize + dilated scatter ============
__global__ __launch_bounds__(256) void out_kernel(
    const float* __restrict__ O, const double* __restrict__ invden,
    float* __restrict__ out)
{
    const int f = blockIdx.x * 256 + threadIdx.x;  // 0 .. 12582911
    const int d  = f & 63;
    const int hh = (f >> 6) % 12;
    const int tk = (f / 768) % 8192;
    const int b  = f / (768 * 8192);

    const int g  = hh >> 2;
    const int gh = hh & 3;
    const int r  = 1 << g;
    const int off = (g == 0) ? 0 : g;

    const int seg = tk >> (11 + g);
    const int pos = tk - (seg << (11 + g));
    const int rem = pos - off;

    float val = 0.f;
    if (rem >= 0 && (rem & (r - 1)) == 0) {
        const int j = rem >> g;
        const int inst = inst_index(g, b, seg, gh);
        float num = O[(long)inst * 131072 + (long)j * 64 + d];
        double iv = invden[(long)(g * 8 + b * 4 + gh) * 64 + d];
        val = (float)((double)num * iv);
    }
    out[f] = val;
}

extern "C" void kernel_launch(void* const* d_in, const int* in_sizes, int n_in,
                              void* d_out, int out_size, void* d_ws, size_t ws_size,
                              hipStream_t stream) {
    const float* q = (const float*)d_in[0];
    const float* k = (const float*)d_in[1];
    const float* v = (const float*)d_in[2];
    float* out = (float*)d_out;

    char* ws = (char*)d_ws;
    double* invden  = (double*)(ws);                       // 12,288 B
    double* partial = (double*)(ws + 12288);               // 196,608 B
    float*  Ows     = (float*)(ws + 208896);               // 29,360,128 B
    unsigned short* Khp  = (unsigned short*)(ws + 29569024);   // 14,680,064 B each
    unsigned short* Klp  = (unsigned short*)(ws + 44249088);
    unsigned short* Vthp = (unsigned short*)(ws + 58929152);
    unsigned short* Vtlp = (unsigned short*)(ws + 73609216);
    // total: 88,289,280 B

    dim3 gprep(32, 56);
    prep_kernel<<<gprep, 256, 0, stream>>>(k, v, Khp, Klp, Vthp, Vtlp);
    attn_kernel<<<896, 256, 0, stream>>>(q, Khp, Klp, Vthp, Vtlp, Ows);
    dim3 gsum(24, 16);
    sum_kernel<<<gsum, 256, 0, stream>>>(Ows, partial);
    inv_kernel<<<24, 64, 0, stream>>>(partial, invden);
    out_kernel<<<49152, 256, 0, stream>>>(Ows, invden, out);
}